// Round 4
// baseline (323.340 us; speedup 1.0000x reference)
//
#include <hip/hip_runtime.h>
#include <stdint.h>

// B=16, C=64, H=128, W=128, HX=HY=64. All I/O fp32.
// Pass X: seq=(b,h) [2048], t=w.  Pass Y: seq=(b,w) [2048], t=h.
// pre2 layout: [t][seq][j] fp32 (d_ws, 67MB) -> contiguous 4KB per block-step.
// d_out serially reused: out_x (f16, 33.5MB) -> final fp32 output (67MB).

#define TLEN 128
#define NSEQ 2048
#define PSTRIDE (NSEQ * 64)   // floats per t-slice

typedef __bf16   bf16x8 __attribute__((ext_vector_type(8)));
typedef _Float16 f16x8  __attribute__((ext_vector_type(8)));
typedef float    f32x4  __attribute__((ext_vector_type(4)));
typedef unsigned short u16x4 __attribute__((ext_vector_type(4)));

static __device__ __forceinline__ float bf2f(unsigned short s){
    union { unsigned int u; float f; } v; v.u = ((unsigned int)s) << 16; return v.f;
}
static __device__ __forceinline__ unsigned short f2bf(float f){
    union { float f; unsigned int u; } v; v.f = f;
    return (unsigned short)((v.u + 0x7FFFu + ((v.u >> 16) & 1u)) >> 16);
}
static __device__ __forceinline__ __bf16 us2b(unsigned short s){
    union { unsigned short u; __bf16 b; } v; v.u = s; return v.b;
}
struct bfpair { __bf16 hi, lo; };
static __device__ __forceinline__ bfpair splitf(float f){
    unsigned short h = f2bf(f);
    bfpair r; r.hi = us2b(h); r.lo = us2b(f2bf(f - bf2f(h))); return r;
}
struct hpair { _Float16 hi, lo; };
static __device__ __forceinline__ hpair splith(float f){
    hpair r; r.hi = (_Float16)f; r.lo = (_Float16)(f - (float)r.hi); return r;
}
static __device__ __forceinline__ float fast_tanh(float x){
    float e = __builtin_amdgcn_exp2f(x * 2.8853900817779268f);
    return 1.0f - 2.0f * __builtin_amdgcn_rcpf(e + 1.0f);
}
// Barrier that does NOT drain vmcnt: LDS-only wait + s_barrier (CK idiom).
static __device__ __forceinline__ void lds_barrier(){
    asm volatile("s_waitcnt lgkmcnt(0)\n\ts_barrier" ::: "memory");
}

// ---------------------------------------------------------------------------
// Projection: pre2[t][seq][j] = sum_k A(r)[k]*Wih[j][k] + bih[j] + bhh[j]
// GEMM row r: PASS0 r=b*16384+h*128+w (A=x NCHW, k=c); PASS1 r=(b*128+w)*128+h
// (A=out_x f16 [b,h,w,j]). Both: prow = (r&127 per-tile)+... unified below.
template<int PASS>
__global__ __launch_bounds__(256) void k_proj(const float* __restrict__ A32,
                                              const unsigned short* __restrict__ A16,
                                              const float* __restrict__ Wih,
                                              const float* __restrict__ b1,
                                              const float* __restrict__ b2,
                                              float* __restrict__ pre){
    int lane = threadIdx.x & 63;
    int wv   = threadIdx.x >> 6;
    int q    = lane >> 4, l15 = lane & 15;

    bf16x8 Wbh[4][2], Wbl[4][2];   // PASS0: bf16 hi/lo split
    f16x8  Wfh[4][2], Wfl[4][2];   // PASS1: f16 hi/lo split
#pragma unroll
    for (int n = 0; n < 4; n++)
#pragma unroll
        for (int kc = 0; kc < 2; kc++){
            const float* p = Wih + (n * 16 + l15) * 64 + kc * 32 + q * 8;
#pragma unroll
            for (int i = 0; i < 8; i++){
                if constexpr (PASS == 0){
                    bfpair s = splitf(p[i]);
                    Wbh[n][kc][i] = s.hi; Wbl[n][kc][i] = s.lo;
                } else {
                    hpair s = splith(p[i]);
                    Wfh[n][kc][i] = s.hi; Wfl[n][kc][i] = s.lo;
                }
            }
        }
    float bias[4];
#pragma unroll
    for (int n = 0; n < 4; n++){
        int j = n * 16 + l15;
        bias[n] = b1[j] + b2[j];
    }

    int row0 = blockIdx.x * 128 + wv * 32;

    // Hoist A loads for both m-tiles (more outstanding loads).
    float av[2][2][8];
    f16x8 Af[2][2];
#pragma unroll
    for (int mi = 0; mi < 2; mi++){
        int r = row0 + mi * 16 + l15;
        if constexpr (PASS == 0){
            int b = r >> 14, hw = r & 16383;
            const float* xb = A32 + (size_t)b * 1048576 + hw;
#pragma unroll
            for (int kc = 0; kc < 2; kc++)
#pragma unroll
                for (int i = 0; i < 8; i++)
                    av[mi][kc][i] = xb[(size_t)(kc * 32 + q * 8 + i) * 16384];
        } else {
            int b = r >> 14, w = (r >> 7) & 127, h = r & 127;
            const unsigned short* xb = A16 + ((size_t)((b * 128 + h) * 128 + w)) * 64;
#pragma unroll
            for (int kc = 0; kc < 2; kc++)
                Af[mi][kc] = *(const f16x8*)(xb + kc * 32 + q * 8);
        }
    }

#pragma unroll
    for (int mi = 0; mi < 2; mi++){
        int rb = row0 + mi * 16;
        f32x4 acc[4];
#pragma unroll
        for (int n = 0; n < 4; n++) acc[n] = (f32x4){bias[n], bias[n], bias[n], bias[n]};

        if constexpr (PASS == 0){
            bf16x8 Ahi[2], Alo[2];
#pragma unroll
            for (int kc = 0; kc < 2; kc++)
#pragma unroll
                for (int i = 0; i < 8; i++){
                    bfpair s = splitf(av[mi][kc][i]);
                    Ahi[kc][i] = s.hi; Alo[kc][i] = s.lo;
                }
#pragma unroll
            for (int n = 0; n < 4; n++)
#pragma unroll
                for (int kc = 0; kc < 2; kc++){
                    acc[n] = __builtin_amdgcn_mfma_f32_16x16x32_bf16(Ahi[kc], Wbh[n][kc], acc[n], 0, 0, 0);
                    acc[n] = __builtin_amdgcn_mfma_f32_16x16x32_bf16(Alo[kc], Wbh[n][kc], acc[n], 0, 0, 0);
                    acc[n] = __builtin_amdgcn_mfma_f32_16x16x32_bf16(Ahi[kc], Wbl[n][kc], acc[n], 0, 0, 0);
                }
        } else {
#pragma unroll
            for (int n = 0; n < 4; n++)
#pragma unroll
                for (int kc = 0; kc < 2; kc++){
                    acc[n] = __builtin_amdgcn_mfma_f32_16x16x32_f16(Af[mi][kc], Wfh[n][kc], acc[n], 0, 0, 0);
                    acc[n] = __builtin_amdgcn_mfma_f32_16x16x32_f16(Af[mi][kc], Wfl[n][kc], acc[n], 0, 0, 0);
                }
        }
        // pre2 row index: prow = (lo7 + q*4 + rr)*2048 + hi*128 + mid
        int lo7 = rb & 127;
        int baseSM = (rb >> 14) * 128 + ((rb >> 7) & 127);
#pragma unroll
        for (int n = 0; n < 4; n++)
#pragma unroll
            for (int rr = 0; rr < 4; rr++)
                pre[(size_t)((lo7 + q * 4 + rr) * 2048 + baseSM) * 64 + n * 16 + l15] = acc[n][rr];
    }
}

// ---------------------------------------------------------------------------
// Scan: h_t = tanh(pre_t + Whh h_{t-1}). 128 blocks x 4 waves; wave wv owns
// j-tile [wv*16, wv*16+16). Whh hi/lo split pinned in VGPRs (A-frags).
// Depth-4 pre prefetch survives barriers (lds_barrier, no vmcnt drain).
// LDS: [par][hi/lo][seq16][64j], 16B-chunk XOR-swizzled by (seq&7).
// PASS 0: out_x f16 [seq][t][j].  PASS 1: final fp32 out[b][j][t][w].
template<int PASS>
__global__ __launch_bounds__(256) void k_scan(const float* __restrict__ pre,
                                              const float* __restrict__ Whh,
                                              unsigned short* __restrict__ outh,
                                              float* __restrict__ outf){
    __shared__ alignas(16) unsigned short hbuf[2][2][16][64];
    int lane = threadIdx.x & 63;
    int wv   = threadIdx.x >> 6;
    int q = lane >> 4, l15 = lane & 15;
    int n0 = blockIdx.x * 16;

    bf16x8 Ahi[2], Alo[2];
#pragma unroll
    for (int kc = 0; kc < 2; kc++){
        const float* p = Whh + (wv * 16 + l15) * 64 + kc * 32 + q * 8;
#pragma unroll
        for (int i = 0; i < 8; i++){
            bfpair s = splitf(p[i]);
            Ahi[kc][i] = s.hi; Alo[kc][i] = s.lo;
        }
    }
    bf16x8 Bhi[2], Blo[2];
#pragma unroll
    for (int kc = 0; kc < 2; kc++)
#pragma unroll
        for (int i = 0; i < 8; i++){ Bhi[kc][i] = us2b(0); Blo[kc][i] = us2b(0); }

    int bb = n0 >> 7, w0 = n0 & 127;

    const float* pb = pre + (size_t)(n0 + l15) * 64 + wv * 16 + q * 4;
    f32x4 buf[4];
#pragma unroll
    for (int d = 0; d < 4; d++) buf[d] = *(const f32x4*)(pb + (size_t)d * PSTRIDE);

    int j0 = wv * 16 + q * 4;
    int e  = l15 & 7;
    int wj  = (((j0 >> 3) ^ e) << 3) | (j0 & 7);   // producer: 8B half-chunk
    int rj0 = ((q)     ^ e) << 3;                   // reader kc=0: 16B chunk
    int rj1 = ((4 + q) ^ e) << 3;                   // reader kc=1

    for (int t = 0; t < TLEN; t += 4){
#pragma unroll
        for (int u = 0; u < 4; u++){
            int tt = t + u;
            f32x4 cur = buf[u];
            int tn = tt + 4;
            if (tn < TLEN) buf[u] = *(const f32x4*)(pb + (size_t)tn * PSTRIDE);

            f32x4 a0 = cur;
            f32x4 a1 = (f32x4){0.f, 0.f, 0.f, 0.f};
            f32x4 a2 = (f32x4){0.f, 0.f, 0.f, 0.f};
            a0 = __builtin_amdgcn_mfma_f32_16x16x32_bf16(Ahi[0], Bhi[0], a0, 0, 0, 0);
            a1 = __builtin_amdgcn_mfma_f32_16x16x32_bf16(Ahi[0], Blo[0], a1, 0, 0, 0);
            a2 = __builtin_amdgcn_mfma_f32_16x16x32_bf16(Alo[0], Bhi[0], a2, 0, 0, 0);
            a0 = __builtin_amdgcn_mfma_f32_16x16x32_bf16(Ahi[1], Bhi[1], a0, 0, 0, 0);
            a1 = __builtin_amdgcn_mfma_f32_16x16x32_bf16(Ahi[1], Blo[1], a1, 0, 0, 0);
            a2 = __builtin_amdgcn_mfma_f32_16x16x32_bf16(Alo[1], Bhi[1], a2, 0, 0, 0);
            f32x4 acc = (a0 + a1) + a2;

            float tv[4]; u16x4 hi4, lo4;
#pragma unroll
            for (int r = 0; r < 4; r++){
                tv[r] = fast_tanh(acc[r]);
                unsigned short h = f2bf(tv[r]);
                hi4[r] = h;
                lo4[r] = f2bf(tv[r] - bf2f(h));
            }
            int par = tt & 1;
            *(u16x4*)&hbuf[par][0][l15][wj] = hi4;
            *(u16x4*)&hbuf[par][1][l15][wj] = lo4;

            if constexpr (PASS == 0){
                u16x4 ov;
#pragma unroll
                for (int r = 0; r < 4; r++){
                    union { _Float16 h; unsigned short s; } c;
                    c.h = (_Float16)tv[r];
                    ov[r] = c.s;
                }
                *(u16x4*)(outh + ((size_t)(n0 + l15) * TLEN + tt) * 64 + j0) = ov;
            } else {
#pragma unroll
                for (int r = 0; r < 4; r++)
                    outf[((size_t)(bb * 64 + j0 + r) * TLEN + tt) * 128 + w0 + l15] = tv[r];
            }
            lds_barrier();
            Bhi[0] = *(const bf16x8*)&hbuf[par][0][l15][rj0];
            Blo[0] = *(const bf16x8*)&hbuf[par][1][l15][rj0];
            Bhi[1] = *(const bf16x8*)&hbuf[par][0][l15][rj1];
            Blo[1] = *(const bf16x8*)&hbuf[par][1][l15][rj1];
        }
    }
}

// ---------------------------------------------------------------------------
extern "C" void kernel_launch(void* const* d_in, const int* in_sizes, int n_in,
                              void* d_out, int out_size, void* d_ws, size_t ws_size,
                              hipStream_t stream){
    (void)in_sizes; (void)n_in; (void)out_size; (void)ws_size;
    const float* x    = (const float*)d_in[0];
    const float* Wihx = (const float*)d_in[1];
    const float* Whhx = (const float*)d_in[2];
    const float* bihx = (const float*)d_in[3];
    const float* bhhx = (const float*)d_in[4];
    const float* Wihy = (const float*)d_in[5];
    const float* Whhy = (const float*)d_in[6];
    const float* bihy = (const float*)d_in[7];
    const float* bhhy = (const float*)d_in[8];
    float* pre = (float*)d_ws;                       // pre2[t][seq][j], 67MB
    unsigned short* oxh = (unsigned short*)d_out;    // out_x f16 staging
    float* of = (float*)d_out;                       // final fp32 output

    k_proj<0><<<2048, 256, 0, stream>>>(x, nullptr, Wihx, bihx, bhhx, pre);
    k_scan<0><<<128,  256, 0, stream>>>(pre, Whhx, oxh, nullptr);
    k_proj<1><<<2048, 256, 0, stream>>>(nullptr, oxh, Wihy, bihy, bhhy, pre);
    k_scan<1><<<128,  256, 0, stream>>>(pre, Whhy, nullptr, of);
}

// Round 5
// 258.150 us; speedup vs baseline: 1.2525x; 1.2525x over previous
//
#include <hip/hip_runtime.h>
#include <stdint.h>

// B=16, C=64, H=128, W=128, HX=HY=64. All I/O fp32.
// Pipeline (3 kernels):
//   k_proj0 : pre_x[t=w][seq=(b,h)][j] (f16, incl bias) = Wihx·x + b
//   k_scan<0>: X recurrence; FUSED Y-projection -> pre_y[t=h][seq=(b,w)][j] (f16, incl bias)
//   k_scan<1>: Y recurrence -> out[b][j][h][w] fp32
// d_ws: pre_x (33.5MB) + pre_y (33.5MB) = 67MB. No out_x staging at all.
// Scan design: barrier-per-step for cross-wave h exchange. ALL global memory
// ops are batched once per 16-step group (reg-slab loads + reg-staged store
// bursts) so 15/16 __syncthreads have no outstanding vmem to drain.

#define TLEN 128
#define NSEQ 2048
#define PSH (NSEQ*64)   // f16 elems per t-slice
#define GT 16           // steps per group

typedef __bf16   bf16x8 __attribute__((ext_vector_type(8)));
typedef _Float16 f16x4  __attribute__((ext_vector_type(4)));
typedef float    f32x4  __attribute__((ext_vector_type(4)));
typedef unsigned short u16x4 __attribute__((ext_vector_type(4)));

static __device__ __forceinline__ unsigned int fbits(float f){
    union { float f; unsigned int u; } v; v.f = f; return v.u;
}
static __device__ __forceinline__ float ubits(unsigned int u){
    union { unsigned int u; float f; } v; v.u = u; return v.f;
}
static __device__ __forceinline__ float bf2f(unsigned short s){ return ubits(((unsigned int)s) << 16); }
static __device__ __forceinline__ unsigned short f2bf(float f){
    unsigned int u = fbits(f);
    return (unsigned short)((u + 0x7FFFu + ((u >> 16) & 1u)) >> 16);
}
static __device__ __forceinline__ __bf16 us2b(unsigned short s){
    union { unsigned short u; __bf16 b; } v; v.u = s; return v.b;
}
struct bfpair { __bf16 hi, lo; };
static __device__ __forceinline__ bfpair splitf(float f){   // RNE split (weights, once)
    unsigned short h = f2bf(f);
    bfpair r; r.hi = us2b(h); r.lo = us2b(f2bf(f - bf2f(h))); return r;
}
static __device__ __forceinline__ float fast_tanh(float x){
    float e = __builtin_amdgcn_exp2f(x * 2.8853900817779268f);
    return 1.0f - 2.0f * __builtin_amdgcn_rcpf(e + 1.0f);
}

// ---------------------------------------------------------------------------
// k_proj0: pre_x[w][b*128+h][j] = f16( sum_c x[b][c][h][w]*Wihx[j][c] + bias )
// bf16 hi/lo 3-term MFMA. Block 256thr/4 waves; wave: 32 rows x 64 j.
__global__ __launch_bounds__(256) void k_proj0(const float* __restrict__ A,
                                               const float* __restrict__ Wih,
                                               const float* __restrict__ b1,
                                               const float* __restrict__ b2,
                                               _Float16* __restrict__ pre){
    int lane = threadIdx.x & 63;
    int wv   = threadIdx.x >> 6;
    int q    = lane >> 4, l15 = lane & 15;

    bf16x8 Whi[4][2], Wlo[4][2];
#pragma unroll
    for (int n = 0; n < 4; n++)
#pragma unroll
        for (int kc = 0; kc < 2; kc++){
            const float* p = Wih + (n * 16 + l15) * 64 + kc * 32 + q * 8;
#pragma unroll
            for (int i = 0; i < 8; i++){
                bfpair s = splitf(p[i]);
                Whi[n][kc][i] = s.hi; Wlo[n][kc][i] = s.lo;
            }
        }
    float bias[4];
#pragma unroll
    for (int n = 0; n < 4; n++){
        int j = n * 16 + l15;
        bias[n] = b1[j] + b2[j];
    }

    int row0 = blockIdx.x * 128 + wv * 32;

    float av[2][2][8];
#pragma unroll
    for (int mi = 0; mi < 2; mi++){
        int r = row0 + mi * 16 + l15;
        int b = r >> 14, hw = r & 16383;
        const float* xb = A + (size_t)b * 1048576 + hw;
#pragma unroll
        for (int kc = 0; kc < 2; kc++)
#pragma unroll
            for (int i = 0; i < 8; i++)
                av[mi][kc][i] = xb[(size_t)(kc * 32 + q * 8 + i) * 16384];
    }

#pragma unroll
    for (int mi = 0; mi < 2; mi++){
        int rb = row0 + mi * 16;
        bf16x8 Ahi[2], Alo[2];
#pragma unroll
        for (int kc = 0; kc < 2; kc++)
#pragma unroll
            for (int i = 0; i < 8; i++){
                bfpair s = splitf(av[mi][kc][i]);
                Ahi[kc][i] = s.hi; Alo[kc][i] = s.lo;
            }
        f32x4 acc[4];
#pragma unroll
        for (int n = 0; n < 4; n++) acc[n] = (f32x4){bias[n], bias[n], bias[n], bias[n]};
#pragma unroll
        for (int n = 0; n < 4; n++)
#pragma unroll
            for (int kc = 0; kc < 2; kc++){
                acc[n] = __builtin_amdgcn_mfma_f32_16x16x32_bf16(Ahi[kc], Whi[n][kc], acc[n], 0, 0, 0);
                acc[n] = __builtin_amdgcn_mfma_f32_16x16x32_bf16(Alo[kc], Whi[n][kc], acc[n], 0, 0, 0);
                acc[n] = __builtin_amdgcn_mfma_f32_16x16x32_bf16(Ahi[kc], Wlo[n][kc], acc[n], 0, 0, 0);
            }
        // rows rb..rb+15 share (b,h); w = (rb&127) + q*4 + rr. seq_x = b*128+h.
        int bT = rb >> 14, hT = (rb >> 7) & 127, wBase = rb & 127;
        size_t seqOff = (size_t)bT * 128 + hT;
#pragma unroll
        for (int n = 0; n < 4; n++)
#pragma unroll
            for (int rr = 0; rr < 4; rr++){
                int w = wBase + q * 4 + rr;
                pre[((size_t)w * NSEQ + seqOff) * 64 + n * 16 + l15] = (_Float16)acc[n][rr];
            }
    }
}

// ---------------------------------------------------------------------------
// k_scan<PASS>: h_t = tanh(pre_t + Whh h_{t-1}), 128 blocks x 4 waves.
// Wave wv owns j-tile [wv*16,+16). Whh hi/lo pinned in VGPRs (A-frags).
// h exchanged via swizzled LDS (parity dbuf) + one __syncthreads per step.
// pre slab (16 steps) loaded into registers at group top; outputs staged in
// registers, burst-stored at group end -> barriers stay vmcnt-clean.
// PASS 0: fused Y-proj on B-frags (h_{t-1}) -> pre_y[t-1] f16 (incl bias_y).
// PASS 1: final out[b][j][t][w] fp32.
template<int PASS>
__global__ __launch_bounds__(256) void k_scan(const _Float16* __restrict__ pre,
                                              const float* __restrict__ Whh,
                                              const float* __restrict__ Wy,
                                              const float* __restrict__ by1,
                                              const float* __restrict__ by2,
                                              _Float16* __restrict__ prey,
                                              float* __restrict__ outf){
    __shared__ alignas(16) unsigned short hbuf[2][2][16][64];
    int lane = threadIdx.x & 63;
    int wv   = threadIdx.x >> 6;
    int q = lane >> 4, l15 = lane & 15;
    int n0 = blockIdx.x * 16;
    int j0 = wv * 16 + q * 4;

    bf16x8 Ahi[2], Alo[2];
#pragma unroll
    for (int kc = 0; kc < 2; kc++){
        const float* p = Whh + (wv * 16 + l15) * 64 + kc * 32 + q * 8;
#pragma unroll
        for (int i = 0; i < 8; i++){
            bfpair s = splitf(p[i]);
            Ahi[kc][i] = s.hi; Alo[kc][i] = s.lo;
        }
    }
    bf16x8 Yhi[2], Ylo[2];
    f32x4  biasy = (f32x4){0.f, 0.f, 0.f, 0.f};
    if constexpr (PASS == 0){
#pragma unroll
        for (int kc = 0; kc < 2; kc++){
            const float* p = Wy + (wv * 16 + l15) * 64 + kc * 32 + q * 8;
#pragma unroll
            for (int i = 0; i < 8; i++){
                bfpair s = splitf(p[i]);
                Yhi[kc][i] = s.hi; Ylo[kc][i] = s.lo;
            }
        }
#pragma unroll
        for (int r = 0; r < 4; r++) biasy[r] = by1[j0 + r] + by2[j0 + r];
    }

    bf16x8 Bhi[2], Blo[2];
#pragma unroll
    for (int kc = 0; kc < 2; kc++)
#pragma unroll
        for (int i = 0; i < 8; i++){ Bhi[kc][i] = us2b(0); Blo[kc][i] = us2b(0); }

    int bb = n0 >> 7, low7 = n0 & 127;   // PASS0: h0 = low7; PASS1: w0 = low7

    const _Float16* pb = pre + (size_t)(n0 + l15) * 64 + j0;
    size_t spy = (size_t)(low7 + l15) * NSEQ + (size_t)bb * 128;  // PASS0 prey seq base

    int e   = l15 & 7;
    int wj  = (((j0 >> 3) ^ e) << 3) | (j0 & 7);
    int rj0 = ((q)     ^ e) << 3;
    int rj1 = ((4 + q) ^ e) << 3;

    f16x4 ps[GT];
    u16x4 prey_st[GT];
    f32x4 outst[GT];

    for (int g = 0; g < TLEN / GT; g++){
        int G = g * GT;
#pragma unroll
        for (int u = 0; u < GT; u++)
            ps[u] = *(const f16x4*)(pb + (size_t)(G + u) * PSH);

#pragma unroll
        for (int u = 0; u < GT; u++){
            int t = G + u;
            // ---- fused Y-proj on current B (= h_{t-1}) -> pre_y[t-1]
            if constexpr (PASS == 0){
                f32x4 y0 = biasy;
                f32x4 y1 = (f32x4){0.f, 0.f, 0.f, 0.f};
                y0 = __builtin_amdgcn_mfma_f32_16x16x32_bf16(Yhi[0], Bhi[0], y0, 0, 0, 0);
                y0 = __builtin_amdgcn_mfma_f32_16x16x32_bf16(Yhi[1], Bhi[1], y0, 0, 0, 0);
                y1 = __builtin_amdgcn_mfma_f32_16x16x32_bf16(Ylo[0], Bhi[0], y1, 0, 0, 0);
                y1 = __builtin_amdgcn_mfma_f32_16x16x32_bf16(Ylo[1], Bhi[1], y1, 0, 0, 0);
                y1 = __builtin_amdgcn_mfma_f32_16x16x32_bf16(Yhi[0], Blo[0], y1, 0, 0, 0);
                y1 = __builtin_amdgcn_mfma_f32_16x16x32_bf16(Yhi[1], Blo[1], y1, 0, 0, 0);
                f32x4 ys = y0 + y1;
#pragma unroll
                for (int r = 0; r < 4; r++){
                    union { _Float16 h; unsigned short s; } c;
                    c.h = (_Float16)ys[r];
                    prey_st[u][r] = c.s;
                }
            }
            // ---- recurrence
            f32x4 a0 = (f32x4){(float)ps[u][0], (float)ps[u][1], (float)ps[u][2], (float)ps[u][3]};
            f32x4 a1 = (f32x4){0.f, 0.f, 0.f, 0.f};
            f32x4 a2 = (f32x4){0.f, 0.f, 0.f, 0.f};
            a0 = __builtin_amdgcn_mfma_f32_16x16x32_bf16(Ahi[0], Bhi[0], a0, 0, 0, 0);
            a1 = __builtin_amdgcn_mfma_f32_16x16x32_bf16(Ahi[0], Blo[0], a1, 0, 0, 0);
            a2 = __builtin_amdgcn_mfma_f32_16x16x32_bf16(Alo[0], Bhi[0], a2, 0, 0, 0);
            a0 = __builtin_amdgcn_mfma_f32_16x16x32_bf16(Ahi[1], Bhi[1], a0, 0, 0, 0);
            a1 = __builtin_amdgcn_mfma_f32_16x16x32_bf16(Ahi[1], Blo[1], a1, 0, 0, 0);
            a2 = __builtin_amdgcn_mfma_f32_16x16x32_bf16(Alo[1], Bhi[1], a2, 0, 0, 0);
            f32x4 acc = (a0 + a1) + a2;

            u16x4 hi4, lo4;
#pragma unroll
            for (int r = 0; r < 4; r++){
                float tv = fast_tanh(acc[r]);
                if constexpr (PASS == 1) outst[u][r] = tv;
                unsigned int ub = fbits(tv);
                hi4[r] = (unsigned short)(ub >> 16);          // trunc-bf16 hi
                float lof = tv - ubits(ub & 0xFFFF0000u);     // exact remainder
                lo4[r] = (unsigned short)(fbits(lof) >> 16);  // trunc-bf16 lo
            }
            int par = t & 1;
            *(u16x4*)&hbuf[par][0][l15][wj] = hi4;
            *(u16x4*)&hbuf[par][1][l15][wj] = lo4;
            __syncthreads();
            Bhi[0] = *(const bf16x8*)&hbuf[par][0][l15][rj0];
            Blo[0] = *(const bf16x8*)&hbuf[par][1][l15][rj0];
            Bhi[1] = *(const bf16x8*)&hbuf[par][0][l15][rj1];
            Blo[1] = *(const bf16x8*)&hbuf[par][1][l15][rj1];
        }
        // ---- burst stores (drained once at next group's first barrier)
        if constexpr (PASS == 0){
#pragma unroll
            for (int u = 0; u < GT; u++){
                int tp = G - 1 + u;
                if (tp >= 0)
                    *(u16x4*)(prey + (spy + tp) * 64 + j0) = prey_st[u];
            }
        } else {
#pragma unroll
            for (int u = 0; u < GT; u++)
#pragma unroll
                for (int r = 0; r < 4; r++)
                    outf[((size_t)(bb * 64 + j0 + r) * TLEN + (G + u)) * 128 + low7 + l15] = outst[u][r];
        }
    }
    // tail: pre_y[127] from final B (= h_127)
    if constexpr (PASS == 0){
        f32x4 y0 = biasy;
        f32x4 y1 = (f32x4){0.f, 0.f, 0.f, 0.f};
        y0 = __builtin_amdgcn_mfma_f32_16x16x32_bf16(Yhi[0], Bhi[0], y0, 0, 0, 0);
        y0 = __builtin_amdgcn_mfma_f32_16x16x32_bf16(Yhi[1], Bhi[1], y0, 0, 0, 0);
        y1 = __builtin_amdgcn_mfma_f32_16x16x32_bf16(Ylo[0], Bhi[0], y1, 0, 0, 0);
        y1 = __builtin_amdgcn_mfma_f32_16x16x32_bf16(Ylo[1], Bhi[1], y1, 0, 0, 0);
        y1 = __builtin_amdgcn_mfma_f32_16x16x32_bf16(Yhi[0], Blo[0], y1, 0, 0, 0);
        y1 = __builtin_amdgcn_mfma_f32_16x16x32_bf16(Yhi[1], Blo[1], y1, 0, 0, 0);
        f32x4 ys = y0 + y1;
        u16x4 pv;
#pragma unroll
        for (int r = 0; r < 4; r++){
            union { _Float16 h; unsigned short s; } c;
            c.h = (_Float16)ys[r];
            pv[r] = c.s;
        }
        *(u16x4*)(prey + (spy + (TLEN - 1)) * 64 + j0) = pv;
    }
}

// ---------------------------------------------------------------------------
extern "C" void kernel_launch(void* const* d_in, const int* in_sizes, int n_in,
                              void* d_out, int out_size, void* d_ws, size_t ws_size,
                              hipStream_t stream){
    (void)in_sizes; (void)n_in; (void)out_size; (void)ws_size;
    const float* x    = (const float*)d_in[0];
    const float* Wihx = (const float*)d_in[1];
    const float* Whhx = (const float*)d_in[2];
    const float* bihx = (const float*)d_in[3];
    const float* bhhx = (const float*)d_in[4];
    const float* Wihy = (const float*)d_in[5];
    const float* Whhy = (const float*)d_in[6];
    const float* bihy = (const float*)d_in[7];
    const float* bhhy = (const float*)d_in[8];
    _Float16* prex = (_Float16*)d_ws;                          // 33.5MB
    _Float16* prey = prex + (size_t)NSEQ * TLEN * 64;          // 33.5MB
    float* of = (float*)d_out;

    k_proj0 <<<2048, 256, 0, stream>>>(x, Wihx, bihx, bhhx, prex);
    k_scan<0><<<128, 256, 0, stream>>>(prex, Whhx, Wihy, bihy, bhhy, prey, nullptr);
    k_scan<1><<<128, 256, 0, stream>>>(prey, Whhy, nullptr, nullptr, nullptr, nullptr, of);
}